// Round 8
// baseline (768.098 us; speedup 1.0000x reference)
//
#include <hip/hip_runtime.h>
#include <hip/hip_bf16.h>
#include <math.h>

typedef unsigned short u16;
typedef unsigned int   u32;
typedef __attribute__((ext_vector_type(8))) short s16x8;
typedef __attribute__((ext_vector_type(4))) float f32x4;

#define CB 768
#define NB 256
#define FB 512
#define BATCH 1024
#define OUTC 131073
#define LOGF 6.2383246250395077f

__device__ __forceinline__ u16 f2bf(float f){
    u32 u = __float_as_uint(f);
    u32 r = u + 0x7FFFu + ((u >> 16) & 1u);
    return (u16)(r >> 16);
}
__device__ __forceinline__ float bf2f(u16 s){ return __uint_as_float(((u32)s) << 16); }
__device__ __forceinline__ bool probe_bf(const void* g){ return ((const u16*)g)[0] == 0x3F80u; }
__device__ __forceinline__ float loadraw(const void* p, size_t i, bool isbf){
    return isbf ? bf2f(((const u16*)p)[i]) : ((const float*)p)[i];
}
__device__ __forceinline__ void split3(float f, u16& h, u16& l, u16& q){
    h = f2bf(f); float r1 = f - bf2f(h);
    l = f2bf(r1); float r2 = r1 - bf2f(l);
    q = f2bf(r2);
}
__device__ __forceinline__ float gelu_f(float x){
    return 0.5f * x * (1.0f + tanhf(0.7978845608028654f * (x + 0.044715f * x * x * x)));
}
__device__ __forceinline__ f32x4 mfma16x16x32(s16x8 a, s16x8 b, f32x4 c){
    return __builtin_amdgcn_mfma_f32_16x16x32_bf16(a, b, c, 0, 0, 0);
}

__device__ __forceinline__ float blockReduce(float v, float* sb, bool domax){
    #pragma unroll
    for (int o = 32; o > 0; o >>= 1){
        float ov = __shfl_down(v, o, 64);
        v = domax ? fmaxf(v, ov) : (v + ov);
    }
    int w = threadIdx.x >> 6, lane = threadIdx.x & 63;
    if (lane == 0) sb[w] = v;
    __syncthreads();
    float r = domax ? fmaxf(fmaxf(sb[0], sb[1]), fmaxf(sb[2], sb[3]))
                    : (sb[0] + sb[1] + sb[2] + sb[3]);
    __syncthreads();
    return r;
}

// ---------- prep: transposes + LN(x)+noop + LN(emb) + coarse/ksel/sumexp init
struct TransDesc { const void* src; u16* dh; u16* dl; int K; int N; int start; int tilesX; };
struct TD6 { TransDesc d[6]; };

#define T_TRANS   3456
#define T_LNX_END 4480   // + 1024 LN(x) blocks
#define T_LEM_END 4736   // + 256 LN(emb) blocks
#define T_CI_END  4752   // + 16 coarse-bias-init blocks
#define T_KS_END  4768   // + 16 ksel-init blocks
#define T_GRID    4769   // + 1 sumexp-zero block

__global__ __launch_bounds__(256) void prep_k(TD6 td,
        const void* x, const void* g, const void* bb, const void* nW, const void* nb,
        const void* emb, const void* ge, const void* be, const void* cb3, const void* ginp,
        u16* __restrict__ xh, u16* __restrict__ xl, u16* __restrict__ xq,
        u16* __restrict__ lnemb, float* __restrict__ noop,
        float* __restrict__ coarse, unsigned char* __restrict__ ksel,
        float* __restrict__ sumexp){
    __shared__ float t[32][33];
    __shared__ float sb[4];
    bool isbf = probe_bf(ginp);
    int blk = blockIdx.x, tid = threadIdx.x;
    if (blk < T_TRANS){
        int e = 0;
        #pragma unroll
        for (int i = 1; i < 6; i++) if (blk >= td.d[i].start) e = i;
        TransDesc d = td.d[e];
        int rel = blk - d.start;
        int n0 = (rel % d.tilesX) * 32;
        int k0 = (rel / d.tilesX) * 32;
        int tx = tid & 31, ty = tid >> 5;
        #pragma unroll
        for (int i = 0; i < 32; i += 8)
            t[ty + i][tx] = loadraw(d.src, (size_t)(k0 + ty + i) * d.N + n0 + tx, isbf);
        __syncthreads();
        #pragma unroll
        for (int i = 0; i < 32; i += 8){
            float f = t[tx][ty + i];
            u16 h = f2bf(f);
            d.dh[(size_t)(n0 + ty + i) * d.K + k0 + tx] = h;
            if (d.dl)
                d.dl[(size_t)(n0 + ty + i) * d.K + k0 + tx] = f2bf(f - bf2f(h));
        }
    } else if (blk < T_LNX_END){
        int b = blk - T_TRANS;
        float v[3];
        #pragma unroll
        for (int i = 0; i < 3; i++) v[i] = loadraw(x, (size_t)b * CB + tid + i * 256, isbf);
        float mean = blockReduce(v[0] + v[1] + v[2], sb, false) * (1.0f / 768.0f);
        float d0 = v[0] - mean, d1 = v[1] - mean, d2 = v[2] - mean;
        float var = blockReduce(d0*d0 + d1*d1 + d2*d2, sb, false) * (1.0f / 768.0f);
        float inv = 1.0f / sqrtf(var + 1e-5f);
        float dot = 0.0f;
        #pragma unroll
        for (int i = 0; i < 3; i++){
            int c = tid + i * 256;
            float xi = (v[i] - mean) * inv * loadraw(g, c, isbf) + loadraw(bb, c, isbf);
            u16 h, l, q; split3(xi, h, l, q);
            size_t o = (size_t)b * CB + c;
            xh[o] = h; xl[o] = l; xq[o] = q;
            dot += xi * loadraw(nW, c, isbf);
        }
        dot = blockReduce(dot, sb, false);
        if (tid == 0) noop[b] = dot + loadraw(nb, 0, isbf);
    } else if (blk < T_LEM_END){
        int n = blk - T_LNX_END;       // LN(emb[n]) once per n (shared by all b)
        float v[3];
        #pragma unroll
        for (int i = 0; i < 3; i++) v[i] = loadraw(emb, (size_t)n * CB + tid + i * 256, isbf);
        float mean = blockReduce(v[0] + v[1] + v[2], sb, false) * (1.0f / 768.0f);
        float d0 = v[0] - mean, d1 = v[1] - mean, d2 = v[2] - mean;
        float var = blockReduce(d0*d0 + d1*d1 + d2*d2, sb, false) * (1.0f / 768.0f);
        float inv = 1.0f / sqrtf(var + 1e-5f);
        #pragma unroll
        for (int i = 0; i < 3; i++){
            int c = tid + i * 256;
            lnemb[(size_t)n * CB + c] =
                f2bf((v[i] - mean) * inv * loadraw(ge, c, isbf) + loadraw(be, c, isbf));
        }
    } else if (blk < T_CI_END){
        int base = (blk - T_LEM_END) * 16384;
        #pragma unroll
        for (int j = 0; j < 64; j++){
            int i = base + j * 256 + tid;
            coarse[i] = loadraw(cb3, i & 255, isbf);
        }
    } else if (blk < T_KS_END){
        int base = (blk - T_CI_END) * 4096;
        u32* kp = (u32*)ksel;
        #pragma unroll
        for (int j = 0; j < 16; j++) kp[base + j * 256 + tid] = 0xFFFFFFFFu;
    } else {
        #pragma unroll
        for (int j = 0; j < 16; j++) sumexp[j * 256 + tid] = 0.0f;
    }
}

// ---------- GEMM body: TMxTN tile, 512 threads = 8 waves (2x4 wave grid),
// BK=64 (two 32-K MFMA sub-steps per LDS stage), register-prefetch pipeline.
// OUTMODE: 0=f32, 1=bf16, 2=split3 planes, 3=atomicAdd f32, 4=f32 + per-row exp-sum atomics
template<int ASPLIT, int BSPLIT, int ACT, int OUTMODE, int TM, int TN, int GATHER>
__device__ __forceinline__ void gemm_body(u16* sm,
        const u16* __restrict__ Ah, const u16* __restrict__ Al, const u16* __restrict__ Aq,
        const int* __restrict__ gidx,
        const u16* __restrict__ Bth, const u16* __restrict__ Btl,
        const void* __restrict__ bias, bool isbf,
        void* __restrict__ o0, void* __restrict__ o1, void* __restrict__ o2,
        int bx, int by, int kbeg, int kend, int N, int lda, int ldb){
    constexpr int LDA = 72;              // 64 + 8 pad (u16)
    constexpr int MT = TM / 32;
    constexpr int NT = TN / 64;
    constexpr int AC = TM / 64;
    constexpr int BC = TN / 64;
    u16* As = sm;
    u16* Bs = sm + ASPLIT * TM * LDA;
    const int m0 = by * TM, n0 = bx * TN;
    const int tid = threadIdx.x;
    const int w = tid >> 6, lane = tid & 63, lm = lane & 15, q = lane >> 4;
    const int wr = w & 1, wc = w >> 1;   // 2x4 wave grid
    f32x4 acc[MT][NT];
    #pragma unroll
    for (int i = 0; i < MT; i++)
        #pragma unroll
        for (int j = 0; j < NT; j++) acc[i][j] = (f32x4)(0.0f);
    const int ar = (AC == 2) ? (tid >> 2) : (tid >> 3);
    const int ac = (AC == 2) ? ((tid & 3) * 16) : ((tid & 7) * 8);
    const int bn = (BC == 2) ? (tid >> 2) : (tid >> 3);
    const int bc = (BC == 2) ? ((tid & 3) * 16) : ((tid & 7) * 8);
    const u16* Apl[3] = { Ah, Al, Aq };
    const u16* Bpl[2] = { Bth, Btl };
    const int arow = GATHER ? gidx[m0 + ar] : (m0 + ar);

    s16x8 pa[ASPLIT][AC], pb[BSPLIT][BC];
    auto load_regs = [&](int kk){
        #pragma unroll
        for (int s = 0; s < ASPLIT; s++){
            const u16* sp = Apl[s] + (size_t)arow * lda + kk + ac;
            pa[s][0] = *(const s16x8*)(sp);
            if (AC == 2) pa[s][1] = *(const s16x8*)(sp + 8);
        }
        #pragma unroll
        for (int s = 0; s < BSPLIT; s++){
            const u16* sp = Bpl[s] + (size_t)(n0 + bn) * ldb + kk + bc;
            pb[s][0] = *(const s16x8*)(sp);
            if (BC == 2) pb[s][1] = *(const s16x8*)(sp + 8);
        }
    };

    load_regs(kbeg);
    for (int k0 = kbeg; k0 < kend; k0 += 64){
        __syncthreads();
        #pragma unroll
        for (int s = 0; s < ASPLIT; s++){
            *(s16x8*)&As[s*TM*LDA + ar*LDA + ac] = pa[s][0];
            if (AC == 2) *(s16x8*)&As[s*TM*LDA + ar*LDA + ac + 8] = pa[s][1];
        }
        #pragma unroll
        for (int s = 0; s < BSPLIT; s++){
            *(s16x8*)&Bs[s*TN*LDA + bn*LDA + bc] = pb[s][0];
            if (BC == 2) *(s16x8*)&Bs[s*TN*LDA + bn*LDA + bc + 8] = pb[s][1];
        }
        __syncthreads();
        if (k0 + 64 < kend) load_regs(k0 + 64);

        #pragma unroll
        for (int kk = 0; kk < 2; kk++){
            s16x8 afr[ASPLIT][MT], bfr[BSPLIT][NT];
            #pragma unroll
            for (int mt = 0; mt < MT; mt++)
                #pragma unroll
                for (int s = 0; s < ASPLIT; s++)
                    afr[s][mt] = *(const s16x8*)&As[s*TM*LDA + ((mt*2 + wr)*16 + lm)*LDA + kk*32 + q*8];
            #pragma unroll
            for (int nt = 0; nt < NT; nt++)
                #pragma unroll
                for (int s = 0; s < BSPLIT; s++)
                    bfr[s][nt] = *(const s16x8*)&Bs[s*TN*LDA + ((nt*4 + wc)*16 + lm)*LDA + kk*32 + q*8];
            #pragma unroll
            for (int mt = 0; mt < MT; mt++)
                #pragma unroll
                for (int nt = 0; nt < NT; nt++){
                    acc[mt][nt] = mfma16x16x32(afr[0][mt], bfr[0][nt], acc[mt][nt]);
                    if (ASPLIT == 3){
                        acc[mt][nt] = mfma16x16x32(afr[1][mt], bfr[0][nt], acc[mt][nt]);
                        acc[mt][nt] = mfma16x16x32(afr[2][mt], bfr[0][nt], acc[mt][nt]);
                    }
                    if (BSPLIT == 2){
                        acc[mt][nt] = mfma16x16x32(afr[0][mt], bfr[1][nt], acc[mt][nt]);
                        if (ASPLIT == 3)
                            acc[mt][nt] = mfma16x16x32(afr[1][mt], bfr[1][nt], acc[mt][nt]);
                    }
                }
        }
    }

    if (OUTMODE == 3){
        #pragma unroll
        for (int nt = 0; nt < NT; nt++){
            int n = n0 + (nt*4 + wc)*16 + lm;
            #pragma unroll
            for (int mt = 0; mt < MT; mt++)
                #pragma unroll
                for (int r = 0; r < 4; r++){
                    int m = m0 + (mt*2 + wr)*16 + q*4 + r;
                    atomicAdd(&((float*)o0)[(size_t)m * N + n], acc[mt][nt][r]);
                }
        }
    } else if (OUTMODE == 4){
        #pragma unroll
        for (int mt = 0; mt < MT; mt++)
            #pragma unroll
            for (int r = 0; r < 4; r++){
                int m = m0 + (mt*2 + wr)*16 + q*4 + r;
                float esum = 0.0f;
                #pragma unroll
                for (int nt = 0; nt < NT; nt++){
                    int n = n0 + (nt*4 + wc)*16 + lm;
                    float vv = acc[mt][nt][r] + (bias ? loadraw(bias, n, isbf) : 0.0f);
                    ((float*)o0)[(size_t)m * N + n] = vv;
                    esum += expf(vv);
                }
                #pragma unroll
                for (int o = 8; o > 0; o >>= 1) esum += __shfl_down(esum, o, 16);
                if (lm == 0) atomicAdd(&((float*)o1)[m], esum);
            }
    } else {
        #pragma unroll
        for (int nt = 0; nt < NT; nt++){
            int n = n0 + (nt*4 + wc)*16 + lm;
            float bv = bias ? loadraw(bias, n, isbf) : 0.0f;
            #pragma unroll
            for (int mt = 0; mt < MT; mt++){
                #pragma unroll
                for (int r = 0; r < 4; r++){
                    int m = m0 + (mt*2 + wr)*16 + q*4 + r;
                    float vv = acc[mt][nt][r] + bv;
                    if (ACT == 1) vv = gelu_f(vv);
                    size_t o = (size_t)m * N + n;
                    if (OUTMODE == 0)      ((float*)o0)[o] = vv;
                    else if (OUTMODE == 1) ((u16*)o0)[o] = f2bf(vv);
                    else {
                        u16 h, l, qq; split3(vv, h, l, qq);
                        ((u16*)o0)[o] = h; ((u16*)o1)[o] = l; ((u16*)o2)[o] = qq;
                    }
                }
            }
        }
    }
}

template<int ASPLIT, int BSPLIT, int ACT, int OUTMODE, int TM, int TN, int GATHER, int MINW>
__global__ __launch_bounds__(512, MINW) void gemm_k(
        const u16* __restrict__ Ah, const u16* __restrict__ Al, const u16* __restrict__ Aq,
        const int* __restrict__ gidx,
        const u16* __restrict__ Bth, const u16* __restrict__ Btl,
        const void* __restrict__ bias, const void* __restrict__ ginp,
        void* __restrict__ o0, void* __restrict__ o1, void* __restrict__ o2,
        int K, int N, int lda, int ldb){
    __shared__ u16 sm[(ASPLIT * TM + BSPLIT * TN) * 72];
    bool isbf = probe_bf(ginp);
    const int kc = K / gridDim.z;
    const int kbeg = blockIdx.z * kc;
    gemm_body<ASPLIT, BSPLIT, ACT, OUTMODE, TM, TN, GATHER>(sm,
        Ah, Al, Aq, gidx, Bth, Btl, bias, isbf, o0, o1, o2,
        blockIdx.x, blockIdx.y, kbeg, kbeg + kc, N, lda, ldb);
}

// ---------- output pass 1: chunks fully determined by coarse+ksel (no routed element,
// no row boundary). Identical decode/rounding to the reference out_k path.
__device__ __forceinline__ void out1_body(const float* __restrict__ coarse,
        const unsigned char* __restrict__ ksel, bool isbf, void* __restrict__ outp,
        u32 ch0, u32 ch1, u32 wtid, u32 stride){
    for (u32 chn = ch0 + wtid; chn < ch1; chn += stride){
        u32 g0 = chn * 8u;
        u32 qq = g0 >> 17;                       // div by 131073 = 2^17 + 1
        int rr = (int)(g0 & 131071u) - (int)qq;
        if (rr < 0){ qq -= 1u; rr += 131073; }
        int b = (int)qq;
        if (rr == 0 || rr >= 131066) continue;   // boundary chunk -> pass 2
        int lastn = -1; float cv = 0.0f; bool defer = false;
        float vals[8];
        #pragma unroll
        for (int e = 0; e < 8; e++){
            int j = rr - 1 + e;
            int n = ((j >> 13) << 4) | ((j >> 5) & 15);
            if (n != lastn){
                lastn = n;
                size_t o = (size_t)b * NB + n;
                cv = coarse[o] - LOGF;
                if (ksel[o] != 255) defer = true;
            }
            vals[e] = cv;
        }
        if (defer) continue;                     // routed element -> pass 2
        if (isbf){
            u16 res[8];
            #pragma unroll
            for (int e = 0; e < 8; e++) res[e] = f2bf(vals[e]);
            *(s16x8*)((u16*)outp + g0) = *(s16x8*)res;
        } else {
            float* of = (float*)outp + g0;
            *(float4*)(of)     = make_float4(vals[0], vals[1], vals[2], vals[3]);
            *(float4*)(of + 4) = make_float4(vals[4], vals[5], vals[6], vals[7]);
        }
    }
}

// GEMM blocks first (dispatched first), then pass-1 writer blocks (co-resident overlap).
// Writers gate nothing downstream except the tiny out2 pass.
template<int ASPLIT, int BSPLIT, int ACT, int OUTMODE, int TM, int TN, int MINW>
__global__ __launch_bounds__(512, MINW) void gemm_out1_k(
        const u16* __restrict__ Ah, const u16* __restrict__ Bth,
        const void* __restrict__ bias, const void* __restrict__ ginp,
        void* __restrict__ o0, void* __restrict__ o1,
        int K, int N, int lda, int ldb, int gemmBlocks, int gx,
        const float* __restrict__ coarse, const unsigned char* __restrict__ ksel,
        void* __restrict__ outp, u32 ch0, u32 ch1){
    __shared__ u16 sm[(ASPLIT * TM + BSPLIT * TN) * 72];
    bool isbf = probe_bf(ginp);
    int blk = blockIdx.x;
    if (blk < gemmBlocks){
        gemm_body<ASPLIT, BSPLIT, ACT, OUTMODE, TM, TN, 0>(sm,
            Ah, nullptr, nullptr, nullptr, Bth, nullptr, bias, isbf,
            o0, o1, nullptr, blk % gx, blk / gx, 0, K, N, lda, ldb);
    } else {
        u32 wblk = (u32)(blk - gemmBlocks);
        u32 nwb  = (u32)(gridDim.x - gemmBlocks);
        out1_body(coarse, ksel, isbf, outp, ch0, ch1,
                  wblk * 512u + (u32)threadIdx.x, nwb * 512u);
    }
}

// ---------- fused per-row top-4 + fine-layer-1 assembly
__global__ __launch_bounds__(512) void topk_fadd_k(const float* __restrict__ coarse,
        unsigned char* __restrict__ ksel, int* __restrict__ idxg,
        const float* __restrict__ embW, const float* __restrict__ xpart,
        const void* __restrict__ fb1, const void* __restrict__ ginp,
        u16* __restrict__ gg1){
    __shared__ int idx_s[32];
    int w = threadIdx.x >> 6, lane = threadIdx.x & 63;
    int b = blockIdx.x * 8 + w;
    const float* cr = coarse + (size_t)b * NB;
    float v[4]; int id[4];
    #pragma unroll
    for (int j = 0; j < 4; j++){ id[j] = lane + 64*j; v[j] = cr[id[j]]; }
    for (int k = 0; k < 4; k++){
        float bv = v[0]; int bi = id[0];
        #pragma unroll
        for (int j = 1; j < 4; j++)
            if (v[j] > bv || (v[j] == bv && id[j] < bi)){ bv = v[j]; bi = id[j]; }
        #pragma unroll
        for (int o = 32; o > 0; o >>= 1){
            float ov = __shfl_xor(bv, o, 64);
            int   oi = __shfl_xor(bi, o, 64);
            if (ov > bv || (ov == bv && oi < bi)){ bv = ov; bi = oi; }
        }
        if (lane == 0){
            idx_s[w*4 + k] = bi;
            idxg[b*4 + k] = bi;
            ksel[(size_t)b * NB + bi] = (unsigned char)k;
        }
        #pragma unroll
        for (int j = 0; j < 4; j++) if (id[j] == bi) v[j] = -INFINITY;
    }
    __syncthreads();
    bool isbf = probe_bf(ginp);
    int fr0 = blockIdx.x * 32;
    #pragma unroll
    for (int j = 0; j < 6; j++){
        int c = (int)threadIdx.x + j * 512;   // 0..3071 chunk id (32 rows x 96 chunks)
        int r = c / 96;
        int col = (c - r * 96) * 8;
        int fr = fr0 + r;
        int bb2 = fr >> 2;
        int n = idx_s[r];
        const float* ew = embW + (size_t)n * CB + col;
        const float* xr = xpart + (size_t)bb2 * CB + col;
        float4 e0 = *(const float4*)ew, e1 = *(const float4*)(ew + 4);
        float4 x0 = *(const float4*)xr, x1 = *(const float4*)(xr + 4);
        float ev[8] = {e0.x,e0.y,e0.z,e0.w,e1.x,e1.y,e1.z,e1.w};
        float xv[8] = {x0.x,x0.y,x0.z,x0.w,x1.x,x1.y,x1.z,x1.w};
        u16 res[8];
        #pragma unroll
        for (int e = 0; e < 8; e++){
            float bv = loadraw(fb1, col + e, isbf);
            res[e] = f2bf(gelu_f((ev[e] + bv) + xv[e]));
        }
        *(s16x8*)(gg1 + (size_t)fr * CB + col) = *(s16x8*)res;
    }
}

// merged launch: coarse layer-1 (blocks 0..191) + xpart GEMM (192..239) + embW GEMM (240..251)
__global__ __launch_bounds__(512, 2) void c1x_k(
        const u16* __restrict__ xh, const u16* __restrict__ xl, const u16* __restrict__ xq,
        const u16* __restrict__ cW1th, const u16* __restrict__ cW1tl,
        const void* __restrict__ cb1, const void* __restrict__ ginp,
        u16* __restrict__ h1h, u16* __restrict__ h1l, u16* __restrict__ h1q,
        const u16* __restrict__ fW1t, float* __restrict__ xpart,
        const u16* __restrict__ lnemb, float* __restrict__ embW){
    __shared__ u16 sm[(3 * 64 + 2 * 64) * 72];
    bool isbf = probe_bf(ginp);
    if (blockIdx.x < 192){
        gemm_body<3, 2, 1, 2, 64, 64, 0>(sm, xh, xl, xq, nullptr, cW1th, cW1tl,
            cb1, isbf, h1h, h1l, h1q, blockIdx.x % 12, blockIdx.x / 12, 0, 768,
            768, 768, 768);
    } else if (blockIdx.x < 240){
        int rel = blockIdx.x - 192;
        gemm_body<1, 1, 0, 0, 128, 128, 0>(sm, xh, nullptr, nullptr, nullptr, fW1t, nullptr,
            nullptr, isbf, xpart, nullptr, nullptr, rel % 6, rel / 6, 0, 768,
            768, 768, 1536);
    } else {
        // embW = lnemb (256x768) @ fW1[768:,:]  -> 256x768 f32
        int rel = blockIdx.x - 240;
        gemm_body<1, 1, 0, 0, 128, 128, 0>(sm, lnemb, nullptr, nullptr, nullptr, fW1t + 768, nullptr,
            nullptr, isbf, embW, nullptr, nullptr, rel % 6, rel / 6, 0, 768,
            768, 768, 1536);
    }
}

// ---------- general single-chunk decode (identical to reference out_k inner body)
__device__ __forceinline__ void out_chunk_general(u32 g0, const float* __restrict__ coarse,
        const float* __restrict__ fine, const float* __restrict__ sumexp,
        const unsigned char* __restrict__ ksel, const float* __restrict__ noop,
        bool isbf, void* __restrict__ outp){
    u32 qq = g0 >> 17;
    int rr = (int)(g0 & 131071u) - (int)qq;
    if (rr < 0){ qq -= 1u; rr += 131073; }
    int b = (int)qq;
    int lastkey = -1, ks = 255, fr = 0;
    float cv = 0.0f, lbase = 0.0f;
    float vals[8];
    #pragma unroll
    for (int e = 0; e < 8; e++){
        float val;
        if (rr == 0){
            val = noop[b];
        } else {
            int j = rr - 1;
            int n = ((j >> 13) << 4) | ((j >> 5) & 15);
            int key = (b << 8) | n;
            if (key != lastkey){
                lastkey = key;
                size_t o = (size_t)b * NB + n;
                cv = coarse[o] - LOGF;
                ks = ksel[o];
                if (ks != 255){
                    fr = b * 4 + ks;
                    lbase = LOGF - logf(sumexp[fr]);
                }
            }
            val = cv;
            if (ks != 255)
                val += fine[((size_t)fr << 9) + (((j >> 9) & 15) << 5) + (j & 31)] + lbase;
        }
        vals[e] = val;
        rr++;
        if (rr == 131073){ rr = 0; b++; }
    }
    if (isbf){
        u16 res[8];
        #pragma unroll
        for (int e = 0; e < 8; e++) res[e] = f2bf(vals[e]);
        *(s16x8*)((u16*)outp + g0) = *(s16x8*)res;
    } else {
        float* of = (float*)outp + g0;
        *(float4*)(of)     = make_float4(vals[0], vals[1], vals[2], vals[3]);
        *(float4*)(of + 4) = make_float4(vals[4], vals[5], vals[6], vals[7]);
    }
}

// ---------- output pass 2: boundary chunks + every chunk overlapping a routed run.
// Duplicate writes across workers produce bitwise-identical values (benign).
__global__ __launch_bounds__(256) void out2_k(const float* __restrict__ coarse,
        const float* __restrict__ fine, const float* __restrict__ sumexp,
        const unsigned char* __restrict__ ksel, const int* __restrict__ idx,
        const float* __restrict__ noop, const void* __restrict__ ginp,
        void* __restrict__ outp){
    bool isbf = probe_bf(ginp);
    if (blockIdx.x == 1024){
        // row-boundary chunks (contain noop + row wrap), one per batch row
        #pragma unroll
        for (int s = 0; s < 4; s++){
            u32 b = (u32)threadIdx.x * 4u + (u32)s;
            u32 g0 = (b * (u32)OUTC) & ~7u;
            out_chunk_general(g0, coarse, fine, sumexp, ksel, noop, isbf, outp);
        }
        return;
    }
    int w = threadIdx.x >> 6, lane = threadIdx.x & 63;
    int u = blockIdx.x * 4 + w;          // routed row fr = u = b*4 + k
    int b = u >> 2;
    int n = idx[u];
    size_t base = (size_t)b * OUTC + 1 + ((size_t)(n >> 4) << 13) + ((size_t)(n & 15) << 5);
    // 16 segments of 32 elements each; each overlaps 4-5 output chunks
    for (int t = lane; t < 16 * 5; t += 64){
        int fh = t / 5, i = t % 5;
        size_t gs = base + ((size_t)fh << 9);
        u32 c = (u32)(gs >> 3) + (u32)i;
        if ((size_t)c * 8u < gs + 32u)
            out_chunk_general(c * 8u, coarse, fine, sumexp, ksel, noop, isbf, outp);
    }
}

extern "C" void kernel_launch(void* const* d_in, const int* in_sizes, int n_in,
                              void* d_out, int out_size, void* d_ws, size_t ws_size,
                              hipStream_t stream){
    (void)in_sizes; (void)n_in; (void)out_size; (void)ws_size;
    char* ws = (char*)d_ws;
    size_t off = 0;
    auto alloc = [&](size_t bytes){ void* p = ws + off; off += (bytes + 255) & ~(size_t)255; return p; };

    u16* xh  = (u16*)alloc((size_t)1024*768*2);
    u16* xl  = (u16*)alloc((size_t)1024*768*2);
    u16* xq  = (u16*)alloc((size_t)1024*768*2);
    u16* h1h = (u16*)alloc((size_t)1024*768*2);
    u16* h1l = (u16*)alloc((size_t)1024*768*2);
    u16* h1q = (u16*)alloc((size_t)1024*768*2);
    u16* h2h = (u16*)alloc((size_t)1024*768*2);
    u16* h2l = (u16*)alloc((size_t)1024*768*2);
    u16* h2q = (u16*)alloc((size_t)1024*768*2);
    u16* lnemb = (u16*)alloc((size_t)256*768*2);
    float* coarse = (float*)alloc((size_t)1024*256*4);
    unsigned char* ksel = (unsigned char*)alloc((size_t)1024*256);
    float* noop   = (float*)alloc((size_t)1024*4);
    float* sumexp = (float*)alloc((size_t)4096*4);
    int*   idx    = (int*)alloc((size_t)4096*4);
    float* embW   = (float*)alloc((size_t)256*768*4);
    float* xpart  = (float*)alloc((size_t)1024*768*4);
    u16*   gg1    = (u16*)  alloc((size_t)4096*768*2);
    u16*   gg2    = (u16*)  alloc((size_t)4096*768*2);
    float* fine   = (float*)alloc((size_t)4096*512*4);
    u16* cW1th = (u16*)alloc((size_t)768*768*2);
    u16* cW1tl = (u16*)alloc((size_t)768*768*2);
    u16* cW2th = (u16*)alloc((size_t)768*768*2);
    u16* cW2tl = (u16*)alloc((size_t)768*768*2);
    u16* cW3th = (u16*)alloc((size_t)768*256*2);
    u16* cW3tl = (u16*)alloc((size_t)768*256*2);
    u16* fW1t  = (u16*)alloc((size_t)768*1536*2);
    u16* fW2t  = (u16*)alloc((size_t)768*768*2);
    u16* fW3t  = (u16*)alloc((size_t)512*768*2);

    const void* ginp = d_in[1];

    TD6 td;
    td.d[0] = { d_in[3],  cW1th, cW1tl,  768, 768,    0, 24 };  // 576 tiles
    td.d[1] = { d_in[5],  cW2th, cW2tl,  768, 768,  576, 24 };  // 576
    td.d[2] = { d_in[7],  cW3th, cW3tl,  768, 256, 1152,  8 };  // 192
    td.d[3] = { d_in[12], fW1t,  nullptr,1536, 768, 1344, 24 }; // 1152
    td.d[4] = { d_in[14], fW2t,  nullptr, 768, 768, 2496, 24 }; // 576
    td.d[5] = { d_in[16], fW3t,  nullptr, 768, 512, 3072, 16 }; // 384 -> 3456

    prep_k<<<T_GRID, 256, 0, stream>>>(td, d_in[0], d_in[1], d_in[2], d_in[18], d_in[19],
            d_in[9], d_in[10], d_in[11], d_in[8], ginp,
            xh, xl, xq, lnemb, noop, coarse, ksel, sumexp);

    // coarse layer 1 (split-3 x split-2) + xpart = xn @ fW1[:768] + embW = lnemb @ fW1[768:]
    c1x_k<<<dim3(252, 1, 1), 512, 0, stream>>>(
            xh, xl, xq, cW1th, cW1tl, d_in[4], ginp, h1h, h1l, h1q,
            fW1t, xpart, lnemb, embW);

    gemm_k<3,2,1,2,64,64,0,2><<<dim3(12, 16, 1), 512, 0, stream>>>(
            h1h, h1l, h1q, nullptr, cW2th, cW2tl,
            d_in[6], ginp, h2h, h2l, h2q, 768, 768, 768, 768);
    gemm_k<3,2,0,3,64,64,0,2><<<dim3(4, 16, 4), 512, 0, stream>>>(
            h2h, h2l, h2q, nullptr, cW3th, cW3tl,
            nullptr, ginp, coarse, nullptr, nullptr, 768, 256, 768, 768);

    // fused: per-row top-4 (ksel + idx) + gg1 = gelu(embW[idx] + fb1 + xpart)
    topk_fadd_k<<<128, 512, 0, stream>>>(coarse, ksel, idx, embW, xpart, d_in[13], ginp, gg1);

    // f2: pure GEMM (dependent f3 starts as soon as it finishes)
    gemm_k<1,1,1,1,64,128,0,4><<<dim3(6, 64, 1), 512, 0, stream>>>(
            gg1, nullptr, nullptr, nullptr, fW2t, nullptr,
            d_in[15], ginp, gg2, nullptr, nullptr, 768, 768, 768, 768);

    const u32 TOTCH = ((u32)BATCH * (u32)OUTC) / 8u;   // 16,777,344

    // f3 GEMM (+ exp-sums, 256 blocks) + ALL out pass-1 writers (1280 blocks).
    // Writers gate only the tiny out2 pass, not any GEMM.
    gemm_out1_k<1,1,0,4,64,128,4><<<dim3(256 + 1280, 1, 1), 512, 0, stream>>>(
            gg2, fW3t, d_in[17], ginp, fine, sumexp,
            768, 512, 768, 768, 256, 4, coarse, ksel, d_out, 0u, TOTCH);

    // pass 2: routed runs + row-boundary chunks (full general decode)
    out2_k<<<1025, 256, 0, stream>>>(coarse, fine, sumexp, ksel, idx, noop, ginp, d_out);
}

// Round 9
// 713.505 us; speedup vs baseline: 1.0765x; 1.0765x over previous
//
#include <hip/hip_runtime.h>
#include <hip/hip_bf16.h>
#include <math.h>

typedef unsigned short u16;
typedef unsigned int   u32;
typedef __attribute__((ext_vector_type(8))) short s16x8;
typedef __attribute__((ext_vector_type(4))) float f32x4;

#define CB 768
#define NB 256
#define FB 512
#define BATCH 1024
#define OUTC 131073
#define LOGF 6.2383246250395077f

__device__ __forceinline__ u16 f2bf(float f){
    u32 u = __float_as_uint(f);
    u32 r = u + 0x7FFFu + ((u >> 16) & 1u);
    return (u16)(r >> 16);
}
__device__ __forceinline__ float bf2f(u16 s){ return __uint_as_float(((u32)s) << 16); }
__device__ __forceinline__ bool probe_bf(const void* g){ return ((const u16*)g)[0] == 0x3F80u; }
__device__ __forceinline__ float loadraw(const void* p, size_t i, bool isbf){
    return isbf ? bf2f(((const u16*)p)[i]) : ((const float*)p)[i];
}
__device__ __forceinline__ void split3(float f, u16& h, u16& l, u16& q){
    h = f2bf(f); float r1 = f - bf2f(h);
    l = f2bf(r1); float r2 = r1 - bf2f(l);
    q = f2bf(r2);
}
__device__ __forceinline__ float gelu_f(float x){
    return 0.5f * x * (1.0f + tanhf(0.7978845608028654f * (x + 0.044715f * x * x * x)));
}
__device__ __forceinline__ f32x4 mfma16x16x32(s16x8 a, s16x8 b, f32x4 c){
    return __builtin_amdgcn_mfma_f32_16x16x32_bf16(a, b, c, 0, 0, 0);
}

__device__ __forceinline__ float blockReduce(float v, float* sb, bool domax){
    #pragma unroll
    for (int o = 32; o > 0; o >>= 1){
        float ov = __shfl_down(v, o, 64);
        v = domax ? fmaxf(v, ov) : (v + ov);
    }
    int w = threadIdx.x >> 6, lane = threadIdx.x & 63;
    if (lane == 0) sb[w] = v;
    __syncthreads();
    float r = domax ? fmaxf(fmaxf(sb[0], sb[1]), fmaxf(sb[2], sb[3]))
                    : (sb[0] + sb[1] + sb[2] + sb[3]);
    __syncthreads();
    return r;
}

// ---------- prep: transposes + LN(x)+noop + LN(emb) + coarse/ksel/sumexp init
struct TransDesc { const void* src; u16* dh; u16* dl; int K; int N; int start; int tilesX; };
struct TD6 { TransDesc d[6]; };

#define T_TRANS   3456
#define T_LNX_END 4480   // + 1024 LN(x) blocks
#define T_LEM_END 4736   // + 256 LN(emb) blocks
#define T_CI_END  4752   // + 16 coarse-bias-init blocks
#define T_KS_END  4768   // + 16 ksel-init blocks
#define T_GRID    4769   // + 1 sumexp-zero block

__global__ __launch_bounds__(256) void prep_k(TD6 td,
        const void* x, const void* g, const void* bb, const void* nW, const void* nb,
        const void* emb, const void* ge, const void* be, const void* cb3, const void* ginp,
        u16* __restrict__ xh, u16* __restrict__ xl, u16* __restrict__ xq,
        u16* __restrict__ lnemb, float* __restrict__ noop,
        float* __restrict__ coarse, unsigned char* __restrict__ ksel,
        float* __restrict__ sumexp){
    __shared__ float t[32][33];
    __shared__ float sb[4];
    bool isbf = probe_bf(ginp);
    int blk = blockIdx.x, tid = threadIdx.x;
    if (blk < T_TRANS){
        int e = 0;
        #pragma unroll
        for (int i = 1; i < 6; i++) if (blk >= td.d[i].start) e = i;
        TransDesc d = td.d[e];
        int rel = blk - d.start;
        int n0 = (rel % d.tilesX) * 32;
        int k0 = (rel / d.tilesX) * 32;
        int tx = tid & 31, ty = tid >> 5;
        #pragma unroll
        for (int i = 0; i < 32; i += 8)
            t[ty + i][tx] = loadraw(d.src, (size_t)(k0 + ty + i) * d.N + n0 + tx, isbf);
        __syncthreads();
        #pragma unroll
        for (int i = 0; i < 32; i += 8){
            float f = t[tx][ty + i];
            u16 h = f2bf(f);
            d.dh[(size_t)(n0 + ty + i) * d.K + k0 + tx] = h;
            if (d.dl)
                d.dl[(size_t)(n0 + ty + i) * d.K + k0 + tx] = f2bf(f - bf2f(h));
        }
    } else if (blk < T_LNX_END){
        int b = blk - T_TRANS;
        float v[3];
        #pragma unroll
        for (int i = 0; i < 3; i++) v[i] = loadraw(x, (size_t)b * CB + tid + i * 256, isbf);
        float mean = blockReduce(v[0] + v[1] + v[2], sb, false) * (1.0f / 768.0f);
        float d0 = v[0] - mean, d1 = v[1] - mean, d2 = v[2] - mean;
        float var = blockReduce(d0*d0 + d1*d1 + d2*d2, sb, false) * (1.0f / 768.0f);
        float inv = 1.0f / sqrtf(var + 1e-5f);
        float dot = 0.0f;
        #pragma unroll
        for (int i = 0; i < 3; i++){
            int c = tid + i * 256;
            float xi = (v[i] - mean) * inv * loadraw(g, c, isbf) + loadraw(bb, c, isbf);
            u16 h, l, q; split3(xi, h, l, q);
            size_t o = (size_t)b * CB + c;
            xh[o] = h; xl[o] = l; xq[o] = q;
            dot += xi * loadraw(nW, c, isbf);
        }
        dot = blockReduce(dot, sb, false);
        if (tid == 0) noop[b] = dot + loadraw(nb, 0, isbf);
    } else if (blk < T_LEM_END){
        int n = blk - T_LNX_END;       // LN(emb[n]) once per n (shared by all b)
        float v[3];
        #pragma unroll
        for (int i = 0; i < 3; i++) v[i] = loadraw(emb, (size_t)n * CB + tid + i * 256, isbf);
        float mean = blockReduce(v[0] + v[1] + v[2], sb, false) * (1.0f / 768.0f);
        float d0 = v[0] - mean, d1 = v[1] - mean, d2 = v[2] - mean;
        float var = blockReduce(d0*d0 + d1*d1 + d2*d2, sb, false) * (1.0f / 768.0f);
        float inv = 1.0f / sqrtf(var + 1e-5f);
        #pragma unroll
        for (int i = 0; i < 3; i++){
            int c = tid + i * 256;
            lnemb[(size_t)n * CB + c] =
                f2bf((v[i] - mean) * inv * loadraw(ge, c, isbf) + loadraw(be, c, isbf));
        }
    } else if (blk < T_CI_END){
        int base = (blk - T_LEM_END) * 16384;
        #pragma unroll
        for (int j = 0; j < 64; j++){
            int i = base + j * 256 + tid;
            coarse[i] = loadraw(cb3, i & 255, isbf);
        }
    } else if (blk < T_KS_END){
        int base = (blk - T_CI_END) * 4096;
        u32* kp = (u32*)ksel;
        #pragma unroll
        for (int j = 0; j < 16; j++) kp[base + j * 256 + tid] = 0xFFFFFFFFu;
    } else {
        #pragma unroll
        for (int j = 0; j < 16; j++) sumexp[j * 256 + tid] = 0.0f;
    }
}

// ---------- GEMM body: TMxTN tile, 512 threads = 8 waves (2x4 wave grid),
// BK=64 (two 32-K MFMA sub-steps per LDS stage), register-prefetch pipeline.
// OUTMODE: 0=f32, 1=bf16, 2=split3 planes, 3=atomicAdd f32, 4=f32 + per-row exp-sum atomics
template<int ASPLIT, int BSPLIT, int ACT, int OUTMODE, int TM, int TN, int GATHER>
__device__ __forceinline__ void gemm_body(u16* sm,
        const u16* __restrict__ Ah, const u16* __restrict__ Al, const u16* __restrict__ Aq,
        const int* __restrict__ gidx,
        const u16* __restrict__ Bth, const u16* __restrict__ Btl,
        const void* __restrict__ bias, bool isbf,
        void* __restrict__ o0, void* __restrict__ o1, void* __restrict__ o2,
        int bx, int by, int kbeg, int kend, int N, int lda, int ldb){
    constexpr int LDA = 72;              // 64 + 8 pad (u16)
    constexpr int MT = TM / 32;
    constexpr int NT = TN / 64;
    constexpr int AC = TM / 64;
    constexpr int BC = TN / 64;
    u16* As = sm;
    u16* Bs = sm + ASPLIT * TM * LDA;
    const int m0 = by * TM, n0 = bx * TN;
    const int tid = threadIdx.x;
    const int w = tid >> 6, lane = tid & 63, lm = lane & 15, q = lane >> 4;
    const int wr = w & 1, wc = w >> 1;   // 2x4 wave grid
    f32x4 acc[MT][NT];
    #pragma unroll
    for (int i = 0; i < MT; i++)
        #pragma unroll
        for (int j = 0; j < NT; j++) acc[i][j] = (f32x4)(0.0f);
    const int ar = (AC == 2) ? (tid >> 2) : (tid >> 3);
    const int ac = (AC == 2) ? ((tid & 3) * 16) : ((tid & 7) * 8);
    const int bn = (BC == 2) ? (tid >> 2) : (tid >> 3);
    const int bc = (BC == 2) ? ((tid & 3) * 16) : ((tid & 7) * 8);
    const u16* Apl[3] = { Ah, Al, Aq };
    const u16* Bpl[2] = { Bth, Btl };
    const int arow = GATHER ? gidx[m0 + ar] : (m0 + ar);

    s16x8 pa[ASPLIT][AC], pb[BSPLIT][BC];
    auto load_regs = [&](int kk){
        #pragma unroll
        for (int s = 0; s < ASPLIT; s++){
            const u16* sp = Apl[s] + (size_t)arow * lda + kk + ac;
            pa[s][0] = *(const s16x8*)(sp);
            if (AC == 2) pa[s][1] = *(const s16x8*)(sp + 8);
        }
        #pragma unroll
        for (int s = 0; s < BSPLIT; s++){
            const u16* sp = Bpl[s] + (size_t)(n0 + bn) * ldb + kk + bc;
            pb[s][0] = *(const s16x8*)(sp);
            if (BC == 2) pb[s][1] = *(const s16x8*)(sp + 8);
        }
    };

    load_regs(kbeg);
    for (int k0 = kbeg; k0 < kend; k0 += 64){
        __syncthreads();
        #pragma unroll
        for (int s = 0; s < ASPLIT; s++){
            *(s16x8*)&As[s*TM*LDA + ar*LDA + ac] = pa[s][0];
            if (AC == 2) *(s16x8*)&As[s*TM*LDA + ar*LDA + ac + 8] = pa[s][1];
        }
        #pragma unroll
        for (int s = 0; s < BSPLIT; s++){
            *(s16x8*)&Bs[s*TN*LDA + bn*LDA + bc] = pb[s][0];
            if (BC == 2) *(s16x8*)&Bs[s*TN*LDA + bn*LDA + bc + 8] = pb[s][1];
        }
        __syncthreads();
        if (k0 + 64 < kend) load_regs(k0 + 64);

        #pragma unroll
        for (int kk = 0; kk < 2; kk++){
            s16x8 afr[ASPLIT][MT], bfr[BSPLIT][NT];
            #pragma unroll
            for (int mt = 0; mt < MT; mt++)
                #pragma unroll
                for (int s = 0; s < ASPLIT; s++)
                    afr[s][mt] = *(const s16x8*)&As[s*TM*LDA + ((mt*2 + wr)*16 + lm)*LDA + kk*32 + q*8];
            #pragma unroll
            for (int nt = 0; nt < NT; nt++)
                #pragma unroll
                for (int s = 0; s < BSPLIT; s++)
                    bfr[s][nt] = *(const s16x8*)&Bs[s*TN*LDA + ((nt*4 + wc)*16 + lm)*LDA + kk*32 + q*8];
            #pragma unroll
            for (int mt = 0; mt < MT; mt++)
                #pragma unroll
                for (int nt = 0; nt < NT; nt++){
                    acc[mt][nt] = mfma16x16x32(afr[0][mt], bfr[0][nt], acc[mt][nt]);
                    if (ASPLIT == 3){
                        acc[mt][nt] = mfma16x16x32(afr[1][mt], bfr[0][nt], acc[mt][nt]);
                        acc[mt][nt] = mfma16x16x32(afr[2][mt], bfr[0][nt], acc[mt][nt]);
                    }
                    if (BSPLIT == 2){
                        acc[mt][nt] = mfma16x16x32(afr[0][mt], bfr[1][nt], acc[mt][nt]);
                        if (ASPLIT == 3)
                            acc[mt][nt] = mfma16x16x32(afr[1][mt], bfr[1][nt], acc[mt][nt]);
                    }
                }
        }
    }

    if (OUTMODE == 3){
        #pragma unroll
        for (int nt = 0; nt < NT; nt++){
            int n = n0 + (nt*4 + wc)*16 + lm;
            #pragma unroll
            for (int mt = 0; mt < MT; mt++)
                #pragma unroll
                for (int r = 0; r < 4; r++){
                    int m = m0 + (mt*2 + wr)*16 + q*4 + r;
                    atomicAdd(&((float*)o0)[(size_t)m * N + n], acc[mt][nt][r]);
                }
        }
    } else if (OUTMODE == 4){
        #pragma unroll
        for (int mt = 0; mt < MT; mt++)
            #pragma unroll
            for (int r = 0; r < 4; r++){
                int m = m0 + (mt*2 + wr)*16 + q*4 + r;
                float esum = 0.0f;
                #pragma unroll
                for (int nt = 0; nt < NT; nt++){
                    int n = n0 + (nt*4 + wc)*16 + lm;
                    float vv = acc[mt][nt][r] + (bias ? loadraw(bias, n, isbf) : 0.0f);
                    ((float*)o0)[(size_t)m * N + n] = vv;
                    esum += expf(vv);
                }
                #pragma unroll
                for (int o = 8; o > 0; o >>= 1) esum += __shfl_down(esum, o, 16);
                if (lm == 0) atomicAdd(&((float*)o1)[m], esum);
            }
    } else {
        #pragma unroll
        for (int nt = 0; nt < NT; nt++){
            int n = n0 + (nt*4 + wc)*16 + lm;
            float bv = bias ? loadraw(bias, n, isbf) : 0.0f;
            #pragma unroll
            for (int mt = 0; mt < MT; mt++){
                #pragma unroll
                for (int r = 0; r < 4; r++){
                    int m = m0 + (mt*2 + wr)*16 + q*4 + r;
                    float vv = acc[mt][nt][r] + bv;
                    if (ACT == 1) vv = gelu_f(vv);
                    size_t o = (size_t)m * N + n;
                    if (OUTMODE == 0)      ((float*)o0)[o] = vv;
                    else if (OUTMODE == 1) ((u16*)o0)[o] = f2bf(vv);
                    else {
                        u16 h, l, qq; split3(vv, h, l, qq);
                        ((u16*)o0)[o] = h; ((u16*)o1)[o] = l; ((u16*)o2)[o] = qq;
                    }
                }
            }
        }
    }
}

template<int ASPLIT, int BSPLIT, int ACT, int OUTMODE, int TM, int TN, int GATHER, int MINW>
__global__ __launch_bounds__(512, MINW) void gemm_k(
        const u16* __restrict__ Ah, const u16* __restrict__ Al, const u16* __restrict__ Aq,
        const int* __restrict__ gidx,
        const u16* __restrict__ Bth, const u16* __restrict__ Btl,
        const void* __restrict__ bias, const void* __restrict__ ginp,
        void* __restrict__ o0, void* __restrict__ o1, void* __restrict__ o2,
        int K, int N, int lda, int ldb){
    __shared__ u16 sm[(ASPLIT * TM + BSPLIT * TN) * 72];
    bool isbf = probe_bf(ginp);
    const int kc = K / gridDim.z;
    const int kbeg = blockIdx.z * kc;
    gemm_body<ASPLIT, BSPLIT, ACT, OUTMODE, TM, TN, GATHER>(sm,
        Ah, Al, Aq, gidx, Bth, Btl, bias, isbf, o0, o1, o2,
        blockIdx.x, blockIdx.y, kbeg, kbeg + kc, N, lda, ldb);
}

// merged launch: coarse layer-1 (blocks 0..191) + xpart GEMM (192..239) + embW GEMM (240..251)
__global__ __launch_bounds__(512, 2) void c1x_k(
        const u16* __restrict__ xh, const u16* __restrict__ xl, const u16* __restrict__ xq,
        const u16* __restrict__ cW1th, const u16* __restrict__ cW1tl,
        const void* __restrict__ cb1, const void* __restrict__ ginp,
        u16* __restrict__ h1h, u16* __restrict__ h1l, u16* __restrict__ h1q,
        const u16* __restrict__ fW1t, float* __restrict__ xpart,
        const u16* __restrict__ lnemb, float* __restrict__ embW){
    __shared__ u16 sm[(3 * 64 + 2 * 64) * 72];
    bool isbf = probe_bf(ginp);
    if (blockIdx.x < 192){
        gemm_body<3, 2, 1, 2, 64, 64, 0>(sm, xh, xl, xq, nullptr, cW1th, cW1tl,
            cb1, isbf, h1h, h1l, h1q, blockIdx.x % 12, blockIdx.x / 12, 0, 768,
            768, 768, 768);
    } else if (blockIdx.x < 240){
        int rel = blockIdx.x - 192;
        gemm_body<1, 1, 0, 0, 128, 128, 0>(sm, xh, nullptr, nullptr, nullptr, fW1t, nullptr,
            nullptr, isbf, xpart, nullptr, nullptr, rel % 6, rel / 6, 0, 768,
            768, 768, 1536);
    } else {
        // embW = lnemb (256x768) @ fW1[768:,:]  -> 256x768 f32
        int rel = blockIdx.x - 240;
        gemm_body<1, 1, 0, 0, 128, 128, 0>(sm, lnemb, nullptr, nullptr, nullptr, fW1t + 768, nullptr,
            nullptr, isbf, embW, nullptr, nullptr, rel % 6, rel / 6, 0, 768,
            768, 768, 1536);
    }
}

// ---------- fused per-row top-4 + fine-layer-1 assembly:
// block = 8 batch rows (1 wave each for top-k), then
// gg1[b*4+k] = gelu(embW[idx] + fb1 + xpart[b]) for this block's 32 routed rows.
__global__ __launch_bounds__(512) void topk_fadd_k(const float* __restrict__ coarse,
        unsigned char* __restrict__ ksel,
        const float* __restrict__ embW, const float* __restrict__ xpart,
        const void* __restrict__ fb1, const void* __restrict__ ginp,
        u16* __restrict__ gg1){
    __shared__ int idx_s[32];
    int w = threadIdx.x >> 6, lane = threadIdx.x & 63;
    int b = blockIdx.x * 8 + w;
    const float* cr = coarse + (size_t)b * NB;
    float v[4]; int id[4];
    #pragma unroll
    for (int j = 0; j < 4; j++){ id[j] = lane + 64*j; v[j] = cr[id[j]]; }
    for (int k = 0; k < 4; k++){
        float bv = v[0]; int bi = id[0];
        #pragma unroll
        for (int j = 1; j < 4; j++)
            if (v[j] > bv || (v[j] == bv && id[j] < bi)){ bv = v[j]; bi = id[j]; }
        #pragma unroll
        for (int o = 32; o > 0; o >>= 1){
            float ov = __shfl_xor(bv, o, 64);
            int   oi = __shfl_xor(bi, o, 64);
            if (ov > bv || (ov == bv && oi < bi)){ bv = ov; bi = oi; }
        }
        if (lane == 0){
            idx_s[w*4 + k] = bi;
            ksel[(size_t)b * NB + bi] = (unsigned char)k;
        }
        #pragma unroll
        for (int j = 0; j < 4; j++) if (id[j] == bi) v[j] = -INFINITY;
    }
    __syncthreads();
    bool isbf = probe_bf(ginp);
    int fr0 = blockIdx.x * 32;
    #pragma unroll
    for (int j = 0; j < 6; j++){
        int c = (int)threadIdx.x + j * 512;   // 0..3071 chunk id (32 rows x 96 chunks)
        int r = c / 96;
        int col = (c - r * 96) * 8;
        int fr = fr0 + r;
        int bb2 = fr >> 2;
        int n = idx_s[r];
        const float* ew = embW + (size_t)n * CB + col;
        const float* xr = xpart + (size_t)bb2 * CB + col;
        float4 e0 = *(const float4*)ew, e1 = *(const float4*)(ew + 4);
        float4 x0 = *(const float4*)xr, x1 = *(const float4*)(xr + 4);
        float ev[8] = {e0.x,e0.y,e0.z,e0.w,e1.x,e1.y,e1.z,e1.w};
        float xv[8] = {x0.x,x0.y,x0.z,x0.w,x1.x,x1.y,x1.z,x1.w};
        u16 res[8];
        #pragma unroll
        for (int e = 0; e < 8; e++){
            float bv = loadraw(fb1, col + e, isbf);
            res[e] = f2bf(gelu_f((ev[e] + bv) + xv[e]));
        }
        *(s16x8*)(gg1 + (size_t)fr * CB + col) = *(s16x8*)res;
    }
}

// ---------- assemble flat output (incremental index decode, (b,n)-state caching)
__global__ __launch_bounds__(256) void out_k(const float* __restrict__ coarse,
        const float* __restrict__ fine, const float* __restrict__ sumexp,
        const unsigned char* __restrict__ ksel, const float* __restrict__ noop,
        const void* __restrict__ ginp, void* __restrict__ outp){
    u32 g0 = ((u32)blockIdx.x * 256u + (u32)threadIdx.x) * 8u;
    const u32 total = (u32)BATCH * (u32)OUTC;
    if (g0 >= total) return;
    bool isbf = probe_bf(ginp);
    u32 qq = g0 >> 17;                       // div by 131073 = 2^17 + 1 (once per thread)
    int rr = (int)(g0 & 131071u) - (int)qq;
    if (rr < 0){ qq -= 1u; rr += 131073; }
    int b = (int)qq;
    int lastkey = -1, ks = 255, fr = 0;
    float cv = 0.0f, lbase = 0.0f;
    float vals[8];
    #pragma unroll
    for (int e = 0; e < 8; e++){
        float val;
        if (rr == 0){
            val = noop[b];
        } else {
            int j = rr - 1;
            int n = ((j >> 13) << 4) | ((j >> 5) & 15);   // ch*16 + cw
            int key = (b << 8) | n;
            if (key != lastkey){
                lastkey = key;
                size_t o = (size_t)b * NB + n;
                cv = coarse[o] - LOGF;
                ks = ksel[o];
                if (ks != 255){
                    fr = b * 4 + ks;
                    lbase = LOGF - logf(sumexp[fr]);
                }
            }
            val = cv;
            if (ks != 255)
                val += fine[((size_t)fr << 9) + (((j >> 9) & 15) << 5) + (j & 31)] + lbase;
        }
        vals[e] = val;
        rr++;
        if (rr == 131073){ rr = 0; b++; }
    }
    if (isbf){
        u16 res[8];
        #pragma unroll
        for (int e = 0; e < 8; e++) res[e] = f2bf(vals[e]);
        *(s16x8*)((u16*)outp + g0) = *(s16x8*)res;
    } else {
        float* of = (float*)outp + g0;
        *(float4*)(of)     = make_float4(vals[0], vals[1], vals[2], vals[3]);
        *(float4*)(of + 4) = make_float4(vals[4], vals[5], vals[6], vals[7]);
    }
}

extern "C" void kernel_launch(void* const* d_in, const int* in_sizes, int n_in,
                              void* d_out, int out_size, void* d_ws, size_t ws_size,
                              hipStream_t stream){
    (void)in_sizes; (void)n_in; (void)out_size; (void)ws_size;
    char* ws = (char*)d_ws;
    size_t off = 0;
    auto alloc = [&](size_t bytes){ void* p = ws + off; off += (bytes + 255) & ~(size_t)255; return p; };

    u16* xh  = (u16*)alloc((size_t)1024*768*2);
    u16* xl  = (u16*)alloc((size_t)1024*768*2);
    u16* xq  = (u16*)alloc((size_t)1024*768*2);
    u16* h1h = (u16*)alloc((size_t)1024*768*2);
    u16* h1l = (u16*)alloc((size_t)1024*768*2);
    u16* h1q = (u16*)alloc((size_t)1024*768*2);
    u16* h2h = (u16*)alloc((size_t)1024*768*2);
    u16* h2l = (u16*)alloc((size_t)1024*768*2);
    u16* h2q = (u16*)alloc((size_t)1024*768*2);
    u16* lnemb = (u16*)alloc((size_t)256*768*2);
    float* coarse = (float*)alloc((size_t)1024*256*4);
    unsigned char* ksel = (unsigned char*)alloc((size_t)1024*256);
    float* noop   = (float*)alloc((size_t)1024*4);
    float* sumexp = (float*)alloc((size_t)4096*4);
    float* embW   = (float*)alloc((size_t)256*768*4);
    float* xpart  = (float*)alloc((size_t)1024*768*4);
    u16*   gg1    = (u16*)  alloc((size_t)4096*768*2);
    u16*   gg2    = (u16*)  alloc((size_t)4096*768*2);
    float* fine   = (float*)alloc((size_t)4096*512*4);
    u16* cW1th = (u16*)alloc((size_t)768*768*2);
    u16* cW1tl = (u16*)alloc((size_t)768*768*2);
    u16* cW2th = (u16*)alloc((size_t)768*768*2);
    u16* cW2tl = (u16*)alloc((size_t)768*768*2);
    u16* cW3th = (u16*)alloc((size_t)768*256*2);
    u16* cW3tl = (u16*)alloc((size_t)768*256*2);
    u16* fW1t  = (u16*)alloc((size_t)768*1536*2);
    u16* fW2t  = (u16*)alloc((size_t)768*768*2);
    u16* fW3t  = (u16*)alloc((size_t)512*768*2);

    const void* ginp = d_in[1];

    TD6 td;
    td.d[0] = { d_in[3],  cW1th, cW1tl,  768, 768,    0, 24 };  // 576 tiles
    td.d[1] = { d_in[5],  cW2th, cW2tl,  768, 768,  576, 24 };  // 576
    td.d[2] = { d_in[7],  cW3th, cW3tl,  768, 256, 1152,  8 };  // 192
    td.d[3] = { d_in[12], fW1t,  nullptr,1536, 768, 1344, 24 }; // 1152
    td.d[4] = { d_in[14], fW2t,  nullptr, 768, 768, 2496, 24 }; // 576
    td.d[5] = { d_in[16], fW3t,  nullptr, 768, 512, 3072, 16 }; // 384 -> 3456

    prep_k<<<T_GRID, 256, 0, stream>>>(td, d_in[0], d_in[1], d_in[2], d_in[18], d_in[19],
            d_in[9], d_in[10], d_in[11], d_in[8], ginp,
            xh, xl, xq, lnemb, noop, coarse, ksel, sumexp);

    // coarse layer 1 (split-3 x split-2) + xpart = xn @ fW1[:768] + embW = lnemb @ fW1[768:]
    c1x_k<<<dim3(252, 1, 1), 512, 0, stream>>>(
            xh, xl, xq, cW1th, cW1tl, d_in[4], ginp, h1h, h1l, h1q,
            fW1t, xpart, lnemb, embW);

    gemm_k<3,2,1,2,64,64,0,2><<<dim3(12, 16, 1), 512, 0, stream>>>(
            h1h, h1l, h1q, nullptr, cW2th, cW2tl,
            d_in[6], ginp, h2h, h2l, h2q, 768, 768, 768, 768);
    gemm_k<3,2,0,3,64,64,0,2><<<dim3(4, 16, 4), 512, 0, stream>>>(
            h2h, h2l, h2q, nullptr, cW3th, cW3tl,
            nullptr, ginp, coarse, nullptr, nullptr, 768, 256, 768, 768);

    // fused: per-row top-4 + gg1 = gelu(embW[idx] + fb1 + xpart)
    topk_fadd_k<<<128, 512, 0, stream>>>(coarse, ksel, embW, xpart, d_in[13], ginp, gg1);

    gemm_k<1,1,1,1,64,128,0,4><<<dim3(6, 64, 1), 512, 0, stream>>>(
            gg1, nullptr, nullptr, nullptr, fW2t, nullptr,
            d_in[15], ginp, gg2, nullptr, nullptr, 768, 768, 768, 768);
    gemm_k<1,1,0,4,64,128,0,4><<<dim3(4, 64, 1), 512, 0, stream>>>(
            gg2, nullptr, nullptr, nullptr, fW3t, nullptr,
            d_in[17], ginp, fine, sumexp, nullptr, 768, 512, 768, 768);

    u32 total_chunks = ((u32)BATCH * (u32)OUTC) / 8u;
    u32 blocks = (total_chunks + 255u) / 256u;
    out_k<<<blocks, 256, 0, stream>>>(coarse, fine, sumexp, ksel, noop, ginp, d_out);
}